// Round 10
// baseline (70.556 us; speedup 1.0000x reference)
//
#include <hip/hip_runtime.h>

#define N_ROIS 32768
#define N_GT   1024
#define N_IMG  8
#define CHUNKS 16                         // lanes cooperating per ROI
#define MBLOCK 256                        // 4 waves
#define MGRID  2048                       // 16 ROIs/block; 6 blocks/CU resident (LDS cap)
#define ROIS_PER_BLOCK (MBLOCK / CHUNKS)  // 16
#define GT_CHUNKS 16                      // 1024 / 64
#define CHUNKS_PER_WAVE 4                 // 16 chunks / 4 waves

// ---------------------------------------------------------------------------
// Single fused kernel (v8). Gain series across occupancy steps (-3.0, -2.7,
// -1.3 us) puts the kernel at ~8 us over a ~58 us harness floor. Last TLP
// lever: 25.1 KB LDS allows 6 blocks/CU; v7 (512-thread blocks, grid 512)
// sat at 2 blocks/CU = 4 waves/SIMD. v8: 256-thread blocks, grid 2048,
// __launch_bounds__(256,6) -> 6 blocks/CU = 6 waves/SIMD to fill the scan's
// serial ds_read->minmax->div chain.
//
// Sort logic (ballot histograms -> wave-0 shfl scan -> stable scatter) is
// bit-identical to v3..v7: within each batch, sorted position order ==
// original-index order, reproducing numpy argmax first-index tie-break.
// ---------------------------------------------------------------------------
__global__ __launch_bounds__(MBLOCK, 6) void roi_target_kernel(
    const float* __restrict__ rois,       // (N_ROIS, 5)
    const int*   __restrict__ roi_b,      // (N_ROIS,)
    const float* __restrict__ gt_boxes,   // (N_GT, 5)
    const int*   __restrict__ gt_b,       // (N_GT,)
    float*       __restrict__ out)        // labels ++ deltas ++ bbwgts
{
    __shared__ float4 s_box[N_GT];        // 16 KB sorted (x1,y1,x2,y2)
    __shared__ float  s_area[N_GT];       //  4 KB sorted area
    __shared__ float  s_lab[N_GT];        //  4 KB sorted label
    __shared__ int    s_chist[GT_CHUNKS][N_IMG];
    __shared__ int    s_cbase[GT_CHUNKS][N_IMG];
    __shared__ int    s_seg[N_IMG + 1];

    int tid  = threadIdx.x;
    int lane = tid & 63;
    int wave = tid >> 6;                  // 0..3; owns chunks 4w..4w+3

    unsigned long long lt_mask = (lane == 63) ? (~0ull >> 1)
                                              : ((1ull << lane) - 1ull);

    // ---- Sort phase 0: prefetch this wave's 4 GT chunks (one round-trip)
    int   bv[CHUNKS_PER_WAVE];
    float bx1[CHUNKS_PER_WAVE], by1[CHUNKS_PER_WAVE];
    float bx2[CHUNKS_PER_WAVE], by2[CHUNKS_PER_WAVE], blab[CHUNKS_PER_WAVE];
    #pragma unroll
    for (int k = 0; k < CHUNKS_PER_WAVE; ++k) {
        int j = (wave * CHUNKS_PER_WAVE + k) * 64 + lane;
        bv[k]   = gt_b[j];
        bx1[k]  = gt_boxes[j * 5 + 0];
        by1[k]  = gt_boxes[j * 5 + 1];
        bx2[k]  = gt_boxes[j * 5 + 2];
        by2[k]  = gt_boxes[j * 5 + 3];
        blab[k] = gt_boxes[j * 5 + 4];
    }

    // ---- Sort phase 1: per-chunk histograms + stable in-chunk ranks
    int rankc[CHUNKS_PER_WAVE];
    #pragma unroll
    for (int k = 0; k < CHUNKS_PER_WAVE; ++k) {
        int b = bv[k];
        unsigned long long mym = 0;
        #pragma unroll
        for (int bb = 0; bb < N_IMG; ++bb) {
            unsigned long long m = __ballot(b == bb);
            if (b == bb) mym = m;
            if (lane == bb) s_chist[wave * CHUNKS_PER_WAVE + k][bb] = __popcll(m);
        }
        rankc[k] = __popcll(mym & lt_mask);
    }
    __syncthreads();

    // ---- Sort phase 2: wave 0 computes chunk bases via in-register shfl scan
    if (wave == 0) {
        int myc    = lane & 15;           // chunk
        int myb_lo = lane >> 4;           // batches (2 slots per lane)
        int myb_hi = myb_lo + 4;
        int cnt_lo = s_chist[myc][myb_lo];
        int cnt_hi = s_chist[myc][myb_hi];
        int inc_lo = cnt_lo, inc_hi = cnt_hi;
        #pragma unroll
        for (int d = 1; d < 16; d <<= 1) {
            int t_lo = __shfl_up(inc_lo, d, 16);
            int t_hi = __shfl_up(inc_hi, d, 16);
            if (myc >= d) { inc_lo += t_lo; inc_hi += t_hi; }
        }
        int t0 = __shfl(inc_lo, 15, 64);
        int t1 = __shfl(inc_lo, 31, 64);
        int t2 = __shfl(inc_lo, 47, 64);
        int t3 = __shfl(inc_lo, 63, 64);
        int t4 = __shfl(inc_hi, 15, 64);
        int t5 = __shfl(inc_hi, 31, 64);
        int t6 = __shfl(inc_hi, 47, 64);
        int t7 = __shfl(inc_hi, 63, 64);

        int s0 = 0;
        int s1 = s0 + t0, s2 = s1 + t1, s3 = s2 + t2, s4 = s3 + t3;
        int s5 = s4 + t4, s6 = s5 + t5, s7 = s6 + t6, s8 = s7 + t7; // == N_GT

        if (lane == 0) {
            s_seg[0] = s0; s_seg[1] = s1; s_seg[2] = s2; s_seg[3] = s3;
            s_seg[4] = s4; s_seg[5] = s5; s_seg[6] = s6; s_seg[7] = s7;
            s_seg[8] = s8;
        }
        int seg_lo = (myb_lo == 0) ? s0 : (myb_lo == 1) ? s1
                   : (myb_lo == 2) ? s2 : s3;
        int seg_hi = (myb_hi == 4) ? s4 : (myb_hi == 5) ? s5
                   : (myb_hi == 6) ? s6 : s7;
        s_cbase[myc][myb_lo] = seg_lo + (inc_lo - cnt_lo);
        s_cbase[myc][myb_hi] = seg_hi + (inc_hi - cnt_hi);
    }
    __syncthreads();

    // ---- Sort phase 3: stable scatter into LDS from prefetched registers
    #pragma unroll
    for (int k = 0; k < CHUNKS_PER_WAVE; ++k) {
        int chunk = wave * CHUNKS_PER_WAVE + k;
        int rank  = s_cbase[chunk][bv[k]] + rankc[k];
        s_box[rank]  = make_float4(bx1[k], by1[k], bx2[k], by2[k]);
        // numpy f32 op order: ((x2-x1)+1) * ((y2-y1)+1)
        s_area[rank] = __fmul_rn(__fadd_rn(__fsub_rn(bx2[k], bx1[k]), 1.0f),
                                 __fadd_rn(__fsub_rn(by2[k], by1[k]), 1.0f));
        s_lab[rank]  = blab[k];
    }
    __syncthreads();

    // ---- ROI phase: 16 lanes per ROI scan the ROI's batch segment (~128 GT).
    int c   = tid & (CHUNKS - 1);
    int roi = blockIdx.x * ROIS_PER_BLOCK + (tid >> 4);

    float rx1 = rois[roi * 5 + 0];
    float ry1 = rois[roi * 5 + 1];
    float rx2 = rois[roi * 5 + 2];
    float ry2 = rois[roi * 5 + 3];
    int   rb  = roi_b[roi];
    float area_r = __fmul_rn(__fadd_rn(__fsub_rn(rx2, rx1), 1.0f),
                             __fadd_rn(__fsub_rn(ry2, ry1), 1.0f));

    int st = s_seg[rb];
    int en = s_seg[rb + 1];

    // Positions increasing per lane, so strict > keeps the first max.
    // Within a batch, position order == original-j order. unroll 2 keeps
    // two independent load->div chains in flight.
    float best = -2.0f;
    int   bp   = -1;
    #pragma unroll 2
    for (int p = st + c; p < en; p += CHUNKS) {
        float4 b  = s_box[p];
        float ix1 = fmaxf(rx1, b.x);
        float iy1 = fmaxf(ry1, b.y);
        float ix2 = fminf(rx2, b.z);
        float iy2 = fminf(ry2, b.w);
        float iw  = fmaxf(__fadd_rn(__fsub_rn(ix2, ix1), 1.0f), 0.0f);
        float ih  = fmaxf(__fadd_rn(__fsub_rn(iy2, iy1), 1.0f), 0.0f);
        float inter = __fmul_rn(iw, ih);
        // union = (area_r + area_g) - inter; contraction blocked (numpy)
        float uni = __fsub_rn(__fadd_rn(area_r, s_area[p]), inter);
        float v   = __fdiv_rn(inter, uni);
        if (v > best) { best = v; bp = p; }
    }

    // Cross-lane reduce over the aligned 16-lane group; equal value -> smaller
    // position wins (== smaller original j within the batch).
    #pragma unroll
    for (int m = 1; m < CHUNKS; m <<= 1) {
        float vo = __shfl_xor(best, m, 64);
        int   po = __shfl_xor(bp,   m, 64);
        if (vo > best || (vo == best && po < bp)) { best = vo; bp = po; }
    }

    if (c == 0) {
        bool fg = (best >= 0.5f);          // bit-exact numpy max (or -2 -> false)
        int  pp = (bp < 0) ? 0 : bp;       // safe index; outputs zeroed if !fg

        float label = fg ? s_lab[pp] : 0.0f;   // integral 1..80, exact

        float4 g  = s_box[pp];
        float ew  = __fadd_rn(__fsub_rn(rx2, rx1), 1.0f);
        float eh  = __fadd_rn(__fsub_rn(ry2, ry1), 1.0f);
        float ecx = __fadd_rn(rx1, __fmul_rn(0.5f, ew));
        float ecy = __fadd_rn(ry1, __fmul_rn(0.5f, eh));
        float gw  = __fadd_rn(__fsub_rn(g.z, g.x), 1.0f);
        float gh  = __fadd_rn(__fsub_rn(g.w, g.y), 1.0f);
        float gcx = __fadd_rn(g.x, __fmul_rn(0.5f, gw));
        float gcy = __fadd_rn(g.y, __fmul_rn(0.5f, gh));

        float dx = __fdiv_rn(__fsub_rn(gcx, ecx), ew);
        float dy = __fdiv_rn(__fsub_rn(gcy, ecy), eh);
        float dw = logf(__fdiv_rn(gw, ew));
        float dh = logf(__fdiv_rn(gh, eh));

        if (!fg) { dx = 0.0f; dy = 0.0f; dw = 0.0f; dh = 0.0f; }
        float wgt = fg ? 1.0f : 0.0f;

        out[roi] = label;
        float4* dout = (float4*)(out + N_ROIS) + roi;
        *dout = make_float4(dx, dy, dw, dh);
        float4* wout = (float4*)(out + N_ROIS + 4 * N_ROIS) + roi;
        *wout = make_float4(wgt, wgt, wgt, wgt);
    }
}

extern "C" void kernel_launch(void* const* d_in, const int* in_sizes, int n_in,
                              void* d_out, int out_size, void* d_ws, size_t ws_size,
                              hipStream_t stream) {
    const float* rois  = (const float*)d_in[0];   // (32768,5)
    const int*   roi_b = (const int*)d_in[1];     // (32768,)
    const float* gt    = (const float*)d_in[2];   // (1024,5)
    const int*   gt_b  = (const int*)d_in[3];     // (1024,)
    float*       out   = (float*)d_out;           // 32768*9 floats

    roi_target_kernel<<<MGRID, MBLOCK, 0, stream>>>(rois, roi_b, gt, gt_b, out);
}

// Round 11
// 66.640 us; speedup vs baseline: 1.0588x; 1.0588x over previous
//
#include <hip/hip_runtime.h>

#define N_ROIS 32768
#define N_GT   1024
#define N_IMG  8
#define CHUNKS 8                          // lanes cooperating per ROI
#define MBLOCK 512                        // 8 waves
#define MGRID  512                        // 2 blocks per CU resident
#define ROIS_PER_BLOCK (MBLOCK / CHUNKS)  // 64 (single pass)
#define GT_CHUNKS 16                      // 1024 / 64
#define CHUNKS_PER_WAVE 2                 // 16 chunks / 8 waves

// ---------------------------------------------------------------------------
// Single fused kernel (v9 == v7, the measured optimum at 66.1 us).
// R10 falsified the "more blocks -> more TLP -> faster" hypothesis: the
// per-block redundant GT sort costs ~0.75 us/block-sort, so grid 2048
// (8 sorts/CU) regressed to 70.6 us vs grid 512 (2 sorts/CU) at 66.1 us.
// Operating points measured: 1 blk/CU: 70.1 | 2 blk/CU (this): 66.1 |
// 6 blk/CU: 70.6. This config is the empirical optimum; residual kernel
// time ~8 us vs ~58 us harness floor (268 MB ws poison-fill dominates).
//
// Sort logic (ballot histograms -> wave-0 shfl scan -> stable scatter):
// within each batch, sorted position order == original-index order,
// reproducing numpy argmax first-index tie-break. All float ops match
// numpy f32 op order with contraction blocked -> bit-identical outputs.
// ---------------------------------------------------------------------------
__global__ __launch_bounds__(MBLOCK, 4) void roi_target_kernel(
    const float* __restrict__ rois,       // (N_ROIS, 5)
    const int*   __restrict__ roi_b,      // (N_ROIS,)
    const float* __restrict__ gt_boxes,   // (N_GT, 5)
    const int*   __restrict__ gt_b,       // (N_GT,)
    float*       __restrict__ out)        // labels ++ deltas ++ bbwgts
{
    __shared__ float4 s_box[N_GT];        // 16 KB sorted (x1,y1,x2,y2)
    __shared__ float  s_area[N_GT];       //  4 KB sorted area
    __shared__ float  s_lab[N_GT];        //  4 KB sorted label
    __shared__ int    s_chist[GT_CHUNKS][N_IMG];
    __shared__ int    s_cbase[GT_CHUNKS][N_IMG];
    __shared__ int    s_seg[N_IMG + 1];

    int tid  = threadIdx.x;
    int lane = tid & 63;
    int wave = tid >> 6;                  // 0..7; owns chunks 2w, 2w+1

    unsigned long long lt_mask = (lane == 63) ? (~0ull >> 1)
                                              : ((1ull << lane) - 1ull);

    // ---- Sort phase 0: prefetch this wave's 2 GT chunks (one round-trip)
    int   bv[CHUNKS_PER_WAVE];
    float bx1[CHUNKS_PER_WAVE], by1[CHUNKS_PER_WAVE];
    float bx2[CHUNKS_PER_WAVE], by2[CHUNKS_PER_WAVE], blab[CHUNKS_PER_WAVE];
    #pragma unroll
    for (int k = 0; k < CHUNKS_PER_WAVE; ++k) {
        int j = (wave * CHUNKS_PER_WAVE + k) * 64 + lane;
        bv[k]   = gt_b[j];
        bx1[k]  = gt_boxes[j * 5 + 0];
        by1[k]  = gt_boxes[j * 5 + 1];
        bx2[k]  = gt_boxes[j * 5 + 2];
        by2[k]  = gt_boxes[j * 5 + 3];
        blab[k] = gt_boxes[j * 5 + 4];
    }

    // ---- Sort phase 1: per-chunk histograms + stable in-chunk ranks
    int rankc[CHUNKS_PER_WAVE];
    #pragma unroll
    for (int k = 0; k < CHUNKS_PER_WAVE; ++k) {
        int b = bv[k];
        unsigned long long mym = 0;
        #pragma unroll
        for (int bb = 0; bb < N_IMG; ++bb) {
            unsigned long long m = __ballot(b == bb);
            if (b == bb) mym = m;
            if (lane == bb) s_chist[wave * CHUNKS_PER_WAVE + k][bb] = __popcll(m);
        }
        rankc[k] = __popcll(mym & lt_mask);
    }
    __syncthreads();

    // ---- Sort phase 2: wave 0 computes chunk bases via in-register shfl scan
    if (wave == 0) {
        int myc    = lane & 15;           // chunk
        int myb_lo = lane >> 4;           // batches (2 slots per lane)
        int myb_hi = myb_lo + 4;
        int cnt_lo = s_chist[myc][myb_lo];
        int cnt_hi = s_chist[myc][myb_hi];
        int inc_lo = cnt_lo, inc_hi = cnt_hi;
        #pragma unroll
        for (int d = 1; d < 16; d <<= 1) {
            int t_lo = __shfl_up(inc_lo, d, 16);
            int t_hi = __shfl_up(inc_hi, d, 16);
            if (myc >= d) { inc_lo += t_lo; inc_hi += t_hi; }
        }
        int t0 = __shfl(inc_lo, 15, 64);
        int t1 = __shfl(inc_lo, 31, 64);
        int t2 = __shfl(inc_lo, 47, 64);
        int t3 = __shfl(inc_lo, 63, 64);
        int t4 = __shfl(inc_hi, 15, 64);
        int t5 = __shfl(inc_hi, 31, 64);
        int t6 = __shfl(inc_hi, 47, 64);
        int t7 = __shfl(inc_hi, 63, 64);

        int s0 = 0;
        int s1 = s0 + t0, s2 = s1 + t1, s3 = s2 + t2, s4 = s3 + t3;
        int s5 = s4 + t4, s6 = s5 + t5, s7 = s6 + t6, s8 = s7 + t7; // == N_GT

        if (lane == 0) {
            s_seg[0] = s0; s_seg[1] = s1; s_seg[2] = s2; s_seg[3] = s3;
            s_seg[4] = s4; s_seg[5] = s5; s_seg[6] = s6; s_seg[7] = s7;
            s_seg[8] = s8;
        }
        int seg_lo = (myb_lo == 0) ? s0 : (myb_lo == 1) ? s1
                   : (myb_lo == 2) ? s2 : s3;
        int seg_hi = (myb_hi == 4) ? s4 : (myb_hi == 5) ? s5
                   : (myb_hi == 6) ? s6 : s7;
        s_cbase[myc][myb_lo] = seg_lo + (inc_lo - cnt_lo);
        s_cbase[myc][myb_hi] = seg_hi + (inc_hi - cnt_hi);
    }
    __syncthreads();

    // ---- Sort phase 3: stable scatter into LDS from prefetched registers
    #pragma unroll
    for (int k = 0; k < CHUNKS_PER_WAVE; ++k) {
        int chunk = wave * CHUNKS_PER_WAVE + k;
        int rank  = s_cbase[chunk][bv[k]] + rankc[k];
        s_box[rank]  = make_float4(bx1[k], by1[k], bx2[k], by2[k]);
        // numpy f32 op order: ((x2-x1)+1) * ((y2-y1)+1)
        s_area[rank] = __fmul_rn(__fadd_rn(__fsub_rn(bx2[k], bx1[k]), 1.0f),
                                 __fadd_rn(__fsub_rn(by2[k], by1[k]), 1.0f));
        s_lab[rank]  = blab[k];
    }
    __syncthreads();

    // ---- ROI phase: 8 lanes per ROI scan the ROI's batch segment (~128 GT).
    // ROI data loaded here (L2-hot; latency hidden by 16 resident waves).
    int c   = tid & (CHUNKS - 1);
    int roi = blockIdx.x * ROIS_PER_BLOCK + (tid >> 3);

    float rx1 = rois[roi * 5 + 0];
    float ry1 = rois[roi * 5 + 1];
    float rx2 = rois[roi * 5 + 2];
    float ry2 = rois[roi * 5 + 3];
    int   rb  = roi_b[roi];
    float area_r = __fmul_rn(__fadd_rn(__fsub_rn(rx2, rx1), 1.0f),
                             __fadd_rn(__fsub_rn(ry2, ry1), 1.0f));

    int st = s_seg[rb];
    int en = s_seg[rb + 1];

    // Positions increasing per lane, so strict > keeps the first max.
    // Within a batch, position order == original-j order. unroll 2 keeps
    // two independent load->div chains in flight.
    float best = -2.0f;
    int   bp   = -1;
    #pragma unroll 2
    for (int p = st + c; p < en; p += CHUNKS) {
        float4 b  = s_box[p];
        float ix1 = fmaxf(rx1, b.x);
        float iy1 = fmaxf(ry1, b.y);
        float ix2 = fminf(rx2, b.z);
        float iy2 = fminf(ry2, b.w);
        float iw  = fmaxf(__fadd_rn(__fsub_rn(ix2, ix1), 1.0f), 0.0f);
        float ih  = fmaxf(__fadd_rn(__fsub_rn(iy2, iy1), 1.0f), 0.0f);
        float inter = __fmul_rn(iw, ih);
        // union = (area_r + area_g) - inter; contraction blocked (numpy)
        float uni = __fsub_rn(__fadd_rn(area_r, s_area[p]), inter);
        float v   = __fdiv_rn(inter, uni);
        if (v > best) { best = v; bp = p; }
    }

    // Cross-lane reduce over the aligned 8-lane group; equal value -> smaller
    // position wins (== smaller original j within the batch).
    #pragma unroll
    for (int m = 1; m < CHUNKS; m <<= 1) {
        float vo = __shfl_xor(best, m, 64);
        int   po = __shfl_xor(bp,   m, 64);
        if (vo > best || (vo == best && po < bp)) { best = vo; bp = po; }
    }

    if (c == 0) {
        bool fg = (best >= 0.5f);          // bit-exact numpy max (or -2 -> false)
        int  pp = (bp < 0) ? 0 : bp;       // safe index; outputs zeroed if !fg

        float label = fg ? s_lab[pp] : 0.0f;   // integral 1..80, exact

        float4 g  = s_box[pp];
        float ew  = __fadd_rn(__fsub_rn(rx2, rx1), 1.0f);
        float eh  = __fadd_rn(__fsub_rn(ry2, ry1), 1.0f);
        float ecx = __fadd_rn(rx1, __fmul_rn(0.5f, ew));
        float ecy = __fadd_rn(ry1, __fmul_rn(0.5f, eh));
        float gw  = __fadd_rn(__fsub_rn(g.z, g.x), 1.0f);
        float gh  = __fadd_rn(__fsub_rn(g.w, g.y), 1.0f);
        float gcx = __fadd_rn(g.x, __fmul_rn(0.5f, gw));
        float gcy = __fadd_rn(g.y, __fmul_rn(0.5f, gh));

        float dx = __fdiv_rn(__fsub_rn(gcx, ecx), ew);
        float dy = __fdiv_rn(__fsub_rn(gcy, ecy), eh);
        float dw = logf(__fdiv_rn(gw, ew));
        float dh = logf(__fdiv_rn(gh, eh));

        if (!fg) { dx = 0.0f; dy = 0.0f; dw = 0.0f; dh = 0.0f; }
        float wgt = fg ? 1.0f : 0.0f;

        out[roi] = label;
        float4* dout = (float4*)(out + N_ROIS) + roi;
        *dout = make_float4(dx, dy, dw, dh);
        float4* wout = (float4*)(out + N_ROIS + 4 * N_ROIS) + roi;
        *wout = make_float4(wgt, wgt, wgt, wgt);
    }
}

extern "C" void kernel_launch(void* const* d_in, const int* in_sizes, int n_in,
                              void* d_out, int out_size, void* d_ws, size_t ws_size,
                              hipStream_t stream) {
    const float* rois  = (const float*)d_in[0];   // (32768,5)
    const int*   roi_b = (const int*)d_in[1];     // (32768,)
    const float* gt    = (const float*)d_in[2];   // (1024,5)
    const int*   gt_b  = (const int*)d_in[3];     // (1024,)
    float*       out   = (float*)d_out;           // 32768*9 floats

    roi_target_kernel<<<MGRID, MBLOCK, 0, stream>>>(rois, roi_b, gt, gt_b, out);
}